// Round 4
// baseline (163.117 us; speedup 1.0000x reference)
//
#include <hip/hip_runtime.h>

#define HW 64
#define NPIX 4096
#define NB 128
#define NA 10
#define HCH 150
#define NT 1024      // threads per block (16 waves; 4 waves/SIMD -> 128-VGPR cap)
#define VS 68        // LDS row stride for r/v (64 + 2 ring + pad)
#define VROWS 66
#define POOLF (2 * VROWS * VS)   // 8976 floats: rlds | vlds (aliases obs region)
#define OS 66        // obs LDS row stride
#define OPL (64 * OS) // obs LDS plane stride (4224)

// ---------------------------------------------------------------------------
// Single fused kernel. One block per batch image. 1024 threads, 2x2 patch per
// thread. R1-R3 lesson: the allocator pins this kernel at 128 VGPRs under
// every launch-bounds/waves-per-eu spelling, and the 512-thread/4x2-patch
// version's ~210-float live set (qr[8][10]+wv[10][9]+vn[6][4]) then spills
// ~13 MB of scratch, leaving the VI loop latency-bound (VALUBusy 17%).
// Fix: shrink the live set under the cap instead of fighting the cap:
//   - 2x2 patch  -> qr[4][10]=40 regs, vn[4][4]=16 (best window/pixel ratio)
//   - wv/wil read per-action from LDS (same-address broadcast, conflict-free),
//     w[9] live only inside one unrolled a-iteration
// ~85 VGPRs live -> spill-free at the forced 128 cap; 16 waves/CU hides LDS
// latency. ALU work per sweep is conserved. VI protocol verbatim (tol 4e-4,
// check every 4th sweep, async in-place sweeps between checks).
// ---------------------------------------------------------------------------
__global__ __launch_bounds__(NT) void vin_fused(
        const float* __restrict__ obs,    // [128][2][64][64]
        const float* __restrict__ Wh,     // [150][2][9]
        const float* __restrict__ bh,     // [150]
        const float* __restrict__ Wr,     // [150][9]
        const float* __restrict__ Wi,     // w_i2q [10][9]
        const float* __restrict__ Wvq,    // w_v2q [10][9]
        const float* __restrict__ Wfc,    // [8][10]
        const int* __restrict__ s1, const int* __restrict__ s2,
        const int* __restrict__ kptr,
        float* __restrict__ out) {        // [128][8]
    __shared__ float pool[POOLF];   // phase 1-3: obs[2][64][66]; phase 4+: rlds|vlds
    __shared__ float whr[4200];     // Wh[2700] | Wr[1350->@2700] | bh[150->@4050]
    __shared__ float kb[222];       // K5[50] C[1]@50 M[162]@51 Bd[9]@213
    __shared__ float wil[90];
    __shared__ float wvl[90];
    __shared__ float wfcl[80];
    __shared__ int   chg[2];
    int tid = threadIdx.x;
    int b = blockIdx.x;

    // ---------------- phase 1: stage everything ----------------
    const float* ob_g = obs + (size_t)b * 2 * NPIX;
    for (int i = tid; i < 2 * NPIX; i += NT) {
        int ch = i >> 12, p = i & 4095, y = p >> 6, x = p & 63;
        pool[ch * OPL + y * OS + x] = ob_g[i];
    }
    for (int i = tid; i < 2700; i += NT) whr[i] = Wh[i];
    for (int i = tid; i < 1350; i += NT) whr[2700 + i] = Wr[i];
    if (tid < 150) whr[4050 + tid] = bh[tid];
    if (tid < 90) { wil[tid] = Wi[tid]; wvl[tid] = Wvq[tid]; }
    if (tid < 80) wfcl[tid] = Wfc[tid];
    if (tid < 2)  chg[tid] = 0;
    int K = kptr[0];
    int att_y = 0, att_x = 0;
    if (tid == 0) { att_y = s1[b]; att_x = s2[b]; }   // tid0-only regs, hide latency
    __syncthreads();

    // ---------------- phase 2: composed-kernel precompute (per wave) --------
    {
        int wvid = tid >> 6, lane = tid & 63;   // 16 waves
        const float* WhL = whr;
        const float* WrL = whr + 2700;
        const float* bhL = whr + 4050;
        for (int o = wvid; o < 222; o += 16) {
            float s = 0.f;
            if (o < 50) {
                int ci = o / 25, uv = o % 25, u = uv / 5, v = uv % 5;
                for (int ch = lane; ch < HCH; ch += 64) {
                    const float* wr = WrL + ch * 9;
                    const float* wh = WhL + ch * 18 + ci * 9;
                    for (int ky = 0; ky < 3; ++ky) {
                        int ey = u - ky; if (ey < 0 || ey > 2) continue;
                        for (int kx = 0; kx < 3; ++kx) {
                            int ex = v - kx; if (ex < 0 || ex > 2) continue;
                            s += wr[ky * 3 + kx] * wh[ey * 3 + ex];
                        }
                    }
                }
            } else if (o == 50) {
                for (int ch = lane; ch < HCH; ch += 64) {
                    float wsum = 0.f;
                    for (int t = 0; t < 9; ++t) wsum += WrL[ch * 9 + t];
                    s += wsum * bhL[ch];
                }
            } else if (o < 213) {
                int m = o - 51;
                int d = m / 18, rest = m % 18, ci = rest / 9, e = rest % 9;
                for (int ch = lane; ch < HCH; ch += 64)
                    s += WrL[ch * 9 + d] * WhL[ch * 18 + ci * 9 + e];
            } else {
                int d = o - 213;
                for (int ch = lane; ch < HCH; ch += 64)
                    s += WrL[ch * 9 + d] * bhL[ch];
            }
            #pragma unroll
            for (int off = 32; off > 0; off >>= 1) s += __shfl_down(s, off);
            if (lane == 0) kb[o] = s;
        }
    }
    __syncthreads();

    // ---------------- phase 3: r in registers (2x2 patch) ----------------
    int tx = tid & 31, ty = tid >> 5;   // 32 x 32 threads
    int x0 = tx * 2, y0 = ty * 2;       // thread owns 2-row x 2-col patch
    float r4[4];
    {
        // zero-padded obs window: rows y0-2..y0+3, cols x0-2..x0+3
        float ow[2][6][6];
        #pragma unroll
        for (int ch = 0; ch < 2; ++ch)
            #pragma unroll
            for (int r = 0; r < 6; ++r) {
                int gy = y0 + r - 2;
                bool yok = (gy >= 0 && gy <= 63);
                #pragma unroll
                for (int c = 0; c < 6; ++c) {
                    int gx = x0 + c - 2;
                    ow[ch][r][c] = (yok && gx >= 0 && gx <= 63)
                        ? pool[ch * OPL + gy * OS + gx] : 0.f;
                }
            }
        float acc[4];
        float C0 = kb[50];
        #pragma unroll
        for (int p = 0; p < 4; ++p) acc[p] = C0;
        #pragma unroll
        for (int u = 0; u < 5; ++u)
            #pragma unroll
            for (int v = 0; v < 5; ++v) {
                float k0 = kb[u * 5 + v];
                float k1 = kb[25 + u * 5 + v];
                #pragma unroll
                for (int py = 0; py < 2; ++py)
                    #pragma unroll
                    for (int px = 0; px < 2; ++px)
                        acc[py * 2 + px] += k0 * ow[0][py + u][px + v]
                                          + k1 * ow[1][py + u][px + v];
            }
        // exact border corrections (edge pixels only)
        #pragma unroll
        for (int py = 0; py < 2; ++py)
            #pragma unroll
            for (int px = 0; px < 2; ++px) {
                int y = y0 + py, x = x0 + px;
                if (y != 0 && y != 63 && x != 0 && x != 63) continue;
                for (int d = 0; d < 9; ++d) {
                    int ny = y + d / 3 - 1, nx = x + d % 3 - 1;
                    if (ny >= 0 && ny <= 63 && nx >= 0 && nx <= 63) continue;
                    float corr = kb[213 + d];
                    for (int e = 0; e < 9; ++e) {
                        int oy = ny + e / 3 - 1, ox = nx + e % 3 - 1;
                        if (oy < 0 || oy > 63 || ox < 0 || ox > 63) continue;
                        corr += kb[51 + d * 18 + e]     * pool[oy * OS + ox]
                              + kb[51 + d * 18 + 9 + e] * pool[OPL + oy * OS + ox];
                    }
                    acc[py * 2 + px] -= corr;
                }
            }
        #pragma unroll
        for (int p = 0; p < 4; ++p) r4[p] = acc[p];
    }
    __syncthreads();                       // all obs reads done; pool retires

    // ---------------- phase 4: pool becomes rlds|vlds ----------------
    for (int i = tid; i < POOLF; i += NT) pool[i] = 0.f;
    __syncthreads();
    float* rlds = pool;
    float* vlds = pool + VROWS * VS;
    #pragma unroll
    for (int py = 0; py < 2; ++py)
        #pragma unroll
        for (int px = 0; px < 2; ++px)
            rlds[(y0 + py + 1) * VS + (x0 + px + 1)] = r4[py * 2 + px];
    __syncthreads();

    // qr[pixel][action] = conv(r, Wi) at pixel; v0 = max_a qr
    float qr[4][NA];
    #pragma unroll
    for (int py = 0; py < 2; ++py) {
        #pragma unroll
        for (int px = 0; px < 2; ++px) {
            int y = y0 + py, x = x0 + px;
            float rn[9];
            #pragma unroll
            for (int t = 0; t < 9; ++t)
                rn[t] = rlds[(y + t / 3) * VS + (x + t % 3)];
            float vmax = -1e30f;
            #pragma unroll
            for (int a = 0; a < NA; ++a) {
                float acc = 0.f;
                #pragma unroll
                for (int t = 0; t < 9; ++t) acc += wil[a * 9 + t] * rn[t];
                qr[py * 2 + px][a] = acc;
                vmax = fmaxf(vmax, acc);
            }
            vlds[(y + 1) * VS + (x + 1)] = vmax;
        }
    }
    __syncthreads();

    // ---------------- phase 5: async value iteration ----------------
    int checks = 0;
    for (int it = 0; it < K; ++it) {
        float vn[4][4];
        #pragma unroll
        for (int r = 0; r < 4; ++r)
            #pragma unroll
            for (int c = 0; c < 4; ++c)
                vn[r][c] = vlds[(y0 + r) * VS + (x0 + c)];
        float nv[4];
        #pragma unroll
        for (int p = 0; p < 4; ++p) nv[p] = -1e30f;
        #pragma unroll
        for (int a = 0; a < NA; ++a) {
            float w[9];                     // per-action weights from LDS
            #pragma unroll
            for (int t = 0; t < 9; ++t) w[t] = wvl[a * 9 + t];
            #pragma unroll
            for (int py = 0; py < 2; ++py)
                #pragma unroll
                for (int px = 0; px < 2; ++px) {
                    float acc = qr[py * 2 + px][a];
                    #pragma unroll
                    for (int ky = 0; ky < 3; ++ky)
                        #pragma unroll
                        for (int kx = 0; kx < 3; ++kx)
                            acc += w[ky * 3 + kx] * vn[py + ky][px + kx];
                    nv[py * 2 + px] = fmaxf(nv[py * 2 + px], acc);
                }
        }
        bool changed = false;
        #pragma unroll
        for (int py = 0; py < 2; ++py)
            #pragma unroll
            for (int px = 0; px < 2; ++px)
                changed |= (fabsf(nv[py * 2 + px] - vn[py + 1][px + 1]) > 4e-4f);
        bool check = ((it & 3) == 3) || (it == K - 1);
        if (check) {
            __syncthreads();   // B1: all reads of this sweep done
            #pragma unroll
            for (int py = 0; py < 2; ++py)
                #pragma unroll
                for (int px = 0; px < 2; ++px)
                    vlds[(y0 + py + 1) * VS + (x0 + px + 1)] = nv[py * 2 + px];
            chg[(checks + 1) & 1] = 0;          // prep next slot
            if (changed) chg[checks & 1] = 1;   // benign same-value race
            __syncthreads();   // B2: v + flags visible
            if (chg[checks & 1] == 0) break;    // full sweep with max|dv|<=tol
            ++checks;
        } else {
            // async in-place sweep: no barrier; races benign (contraction)
            #pragma unroll
            for (int py = 0; py < 2; ++py)
                #pragma unroll
                for (int px = 0; px < 2; ++px)
                    vlds[(y0 + py + 1) * VS + (x0 + px + 1)] = nv[py * 2 + px];
            __threadfence_block();   // visibility + defeat LDS caching
        }
    }

    // ---------------- phase 6: attended q + FC ----------------
    if (tid == 0) {
        int yy = att_y, xx = att_x;
        float q[NA];
        #pragma unroll
        for (int a = 0; a < NA; ++a) {
            float acc = 0.f;
            #pragma unroll
            for (int t = 0; t < 9; ++t) {
                int ly = yy + t / 3, lx = xx + t % 3;
                acc += wil[a * 9 + t] * rlds[ly * VS + lx]
                     + wvl[a * 9 + t] * vlds[ly * VS + lx];
            }
            q[a] = acc;
        }
        #pragma unroll
        for (int n = 0; n < 8; ++n) {
            float o = 0.f;
            #pragma unroll
            for (int a = 0; a < NA; ++a) o += q[a] * wfcl[n * NA + a];
            out[b * 8 + n] = o;
        }
    }
}

// ---------------------------------------------------------------------------
extern "C" void kernel_launch(void* const* d_in, const int* in_sizes, int n_in,
                              void* d_out, int out_size, void* d_ws, size_t ws_size,
                              hipStream_t stream) {
    const int*   s1   = (const int*)d_in[0];
    const int*   s2   = (const int*)d_in[1];
    const float* obs  = (const float*)d_in[2];
    const int*   kptr = (const int*)d_in[3];
    const float* Wh   = (const float*)d_in[4];
    const float* bh   = (const float*)d_in[5];
    const float* Wr   = (const float*)d_in[6];
    const float* Wi   = (const float*)d_in[7];
    const float* Wvq  = (const float*)d_in[8];
    const float* Wfc  = (const float*)d_in[9];
    float* out = (float*)d_out;
    (void)ws_size; (void)d_ws; (void)in_sizes; (void)n_in; (void)out_size;

    vin_fused<<<NB, NT, 0, stream>>>(obs, Wh, bh, Wr, Wi, Wvq, Wfc,
                                     s1, s2, kptr, out);
}

// Round 5
// 143.970 us; speedup vs baseline: 1.1330x; 1.1330x over previous
//
#include <hip/hip_runtime.h>

#define HW 64
#define NPIX 4096
#define NB 128
#define NA 10
#define HCH 150
#define NT 1024      // threads per block (16 waves)
#define VS 68        // LDS row stride for r/v (64 + 2 ring + pad)
#define VROWS 66
#define POOLF (2 * VROWS * VS)   // 8976 floats: rlds | vlds (aliases obs region)
#define OS 66        // obs LDS row stride
#define OPL (64 * OS) // obs LDS plane stride (4224)
#define PADF 8448    // 33792 B LDS pad -> total ~88.5 KB so ONE block/CU

// ---------------------------------------------------------------------------
// Single fused kernel. One block per batch image. 1024 threads, 2x2 patch.
//
// R1-R4 allocator forensics: the VGPR budget tracks LDS-limited occupancy.
// Static LDS 54.8 KB -> 2 blocks/CU fit -> at 512 thr the budget is 128
// (R1-R3), at 1024 thr it is 64 (R4, 81 MB spill traffic). launch_bounds /
// amdgpu_waves_per_eu never moved it. Fix: pad static LDS past 81,920 B so
// LDS allows only ONE block/CU (we launch 128 blocks on 256 CUs - one per CU
// is all we use). 1024-thr block then = 4 waves/SIMD -> 128-VGPR budget; the
// 2x2-patch VI live set (qr[4][10]=40 + vn[4][4]=16 + nv[4] + w[9] + addr
// ~ 85) fits spill-free, with 16 waves/CU latency hiding.
//   - wv/wil read per-action from LDS (same-address broadcast, conflict-free)
// VI protocol verbatim (tol 4e-4, check every 4th sweep, async in-place
// sweeps between checks; benign races - contraction map).
// ---------------------------------------------------------------------------
__global__ __launch_bounds__(NT) void vin_fused(
        const float* __restrict__ obs,    // [128][2][64][64]
        const float* __restrict__ Wh,     // [150][2][9]
        const float* __restrict__ bh,     // [150]
        const float* __restrict__ Wr,     // [150][9]
        const float* __restrict__ Wi,     // w_i2q [10][9]
        const float* __restrict__ Wvq,    // w_v2q [10][9]
        const float* __restrict__ Wfc,    // [8][10]
        const int* __restrict__ s1, const int* __restrict__ s2,
        const int* __restrict__ kptr,
        float* __restrict__ out) {        // [128][8]
    __shared__ float pool[POOLF];   // phase 1-3: obs[2][64][66]; phase 4+: rlds|vlds
    __shared__ float whr[4200];     // Wh[2700] | Wr[1350->@2700] | bh[150->@4050]
    __shared__ float kb[222];       // K5[50] C[1]@50 M[162]@51 Bd[9]@213
    __shared__ float wil[90];
    __shared__ float wvl[90];
    __shared__ float wfcl[80];
    __shared__ int   chg[2];
    __shared__ float ldspad[PADF];  // occupancy shaper: forces 1 block/CU so the
                                    // allocator budgets 128 VGPRs (see header)
    int tid = threadIdx.x;
    int b = blockIdx.x;

    // ---------------- phase 1: stage everything ----------------
    const float* ob_g = obs + (size_t)b * 2 * NPIX;
    for (int i = tid; i < 2 * NPIX; i += NT) {
        int ch = i >> 12, p = i & 4095, y = p >> 6, x = p & 63;
        pool[ch * OPL + y * OS + x] = ob_g[i];
    }
    for (int i = tid; i < 2700; i += NT) whr[i] = Wh[i];
    for (int i = tid; i < 1350; i += NT) whr[2700 + i] = Wr[i];
    if (tid < 150) whr[4050 + tid] = bh[tid];
    if (tid < 90) { wil[tid] = Wi[tid]; wvl[tid] = Wvq[tid]; }
    if (tid < 80) wfcl[tid] = Wfc[tid];
    if (tid < 2)  chg[tid] = 0;
    int K = kptr[0];
    int att_y = 0, att_x = 0;
    if (tid == 0) { att_y = s1[b]; att_x = s2[b]; }   // tid0-only regs, hide latency
    __syncthreads();

    // ---------------- phase 2: composed-kernel precompute (per wave) --------
    {
        int wvid = tid >> 6, lane = tid & 63;   // 16 waves
        const float* WhL = whr;
        const float* WrL = whr + 2700;
        const float* bhL = whr + 4050;
        for (int o = wvid; o < 222; o += 16) {
            float s = 0.f;
            if (o < 50) {
                int ci = o / 25, uv = o % 25, u = uv / 5, v = uv % 5;
                for (int ch = lane; ch < HCH; ch += 64) {
                    const float* wr = WrL + ch * 9;
                    const float* wh = WhL + ch * 18 + ci * 9;
                    for (int ky = 0; ky < 3; ++ky) {
                        int ey = u - ky; if (ey < 0 || ey > 2) continue;
                        for (int kx = 0; kx < 3; ++kx) {
                            int ex = v - kx; if (ex < 0 || ex > 2) continue;
                            s += wr[ky * 3 + kx] * wh[ey * 3 + ex];
                        }
                    }
                }
            } else if (o == 50) {
                for (int ch = lane; ch < HCH; ch += 64) {
                    float wsum = 0.f;
                    for (int t = 0; t < 9; ++t) wsum += WrL[ch * 9 + t];
                    s += wsum * bhL[ch];
                }
            } else if (o < 213) {
                int m = o - 51;
                int d = m / 18, rest = m % 18, ci = rest / 9, e = rest % 9;
                for (int ch = lane; ch < HCH; ch += 64)
                    s += WrL[ch * 9 + d] * WhL[ch * 18 + ci * 9 + e];
            } else {
                int d = o - 213;
                for (int ch = lane; ch < HCH; ch += 64)
                    s += WrL[ch * 9 + d] * bhL[ch];
            }
            #pragma unroll
            for (int off = 32; off > 0; off >>= 1) s += __shfl_down(s, off);
            if (lane == 0) kb[o] = s;
        }
    }
    __syncthreads();

    // ---------------- phase 3: r in registers (2x2 patch) ----------------
    int tx = tid & 31, ty = tid >> 5;   // 32 x 32 threads
    int x0 = tx * 2, y0 = ty * 2;       // thread owns 2-row x 2-col patch
    float r4[4];
    {
        // zero-padded obs window: rows y0-2..y0+3, cols x0-2..x0+3
        float ow[2][6][6];
        #pragma unroll
        for (int ch = 0; ch < 2; ++ch)
            #pragma unroll
            for (int r = 0; r < 6; ++r) {
                int gy = y0 + r - 2;
                bool yok = (gy >= 0 && gy <= 63);
                #pragma unroll
                for (int c = 0; c < 6; ++c) {
                    int gx = x0 + c - 2;
                    ow[ch][r][c] = (yok && gx >= 0 && gx <= 63)
                        ? pool[ch * OPL + gy * OS + gx] : 0.f;
                }
            }
        float acc[4];
        float C0 = kb[50];
        #pragma unroll
        for (int p = 0; p < 4; ++p) acc[p] = C0;
        #pragma unroll
        for (int u = 0; u < 5; ++u)
            #pragma unroll
            for (int v = 0; v < 5; ++v) {
                float k0 = kb[u * 5 + v];
                float k1 = kb[25 + u * 5 + v];
                #pragma unroll
                for (int py = 0; py < 2; ++py)
                    #pragma unroll
                    for (int px = 0; px < 2; ++px)
                        acc[py * 2 + px] += k0 * ow[0][py + u][px + v]
                                          + k1 * ow[1][py + u][px + v];
            }
        // exact border corrections (edge pixels only)
        #pragma unroll
        for (int py = 0; py < 2; ++py)
            #pragma unroll
            for (int px = 0; px < 2; ++px) {
                int y = y0 + py, x = x0 + px;
                if (y != 0 && y != 63 && x != 0 && x != 63) continue;
                for (int d = 0; d < 9; ++d) {
                    int ny = y + d / 3 - 1, nx = x + d % 3 - 1;
                    if (ny >= 0 && ny <= 63 && nx >= 0 && nx <= 63) continue;
                    float corr = kb[213 + d];
                    for (int e = 0; e < 9; ++e) {
                        int oy = ny + e / 3 - 1, ox = nx + e % 3 - 1;
                        if (oy < 0 || oy > 63 || ox < 0 || ox > 63) continue;
                        corr += kb[51 + d * 18 + e]     * pool[oy * OS + ox]
                              + kb[51 + d * 18 + 9 + e] * pool[OPL + oy * OS + ox];
                    }
                    acc[py * 2 + px] -= corr;
                }
            }
        #pragma unroll
        for (int p = 0; p < 4; ++p) r4[p] = acc[p];
    }
    __syncthreads();                       // all obs reads done; pool retires

    // ---------------- phase 4: pool becomes rlds|vlds ----------------
    for (int i = tid; i < POOLF; i += NT) pool[i] = 0.f;
    __syncthreads();
    float* rlds = pool;
    float* vlds = pool + VROWS * VS;
    #pragma unroll
    for (int py = 0; py < 2; ++py)
        #pragma unroll
        for (int px = 0; px < 2; ++px)
            rlds[(y0 + py + 1) * VS + (x0 + px + 1)] = r4[py * 2 + px];
    __syncthreads();

    // qr[pixel][action] = conv(r, Wi) at pixel; v0 = max_a qr
    float qr[4][NA];
    #pragma unroll
    for (int py = 0; py < 2; ++py) {
        #pragma unroll
        for (int px = 0; px < 2; ++px) {
            int y = y0 + py, x = x0 + px;
            float rn[9];
            #pragma unroll
            for (int t = 0; t < 9; ++t)
                rn[t] = rlds[(y + t / 3) * VS + (x + t % 3)];
            float vmax = -1e30f;
            #pragma unroll
            for (int a = 0; a < NA; ++a) {
                float acc = 0.f;
                #pragma unroll
                for (int t = 0; t < 9; ++t) acc += wil[a * 9 + t] * rn[t];
                qr[py * 2 + px][a] = acc;
                vmax = fmaxf(vmax, acc);
            }
            vlds[(y + 1) * VS + (x + 1)] = vmax;
        }
    }
    __syncthreads();

    // ---------------- phase 5: async value iteration ----------------
    int checks = 0;
    for (int it = 0; it < K; ++it) {
        float vn[4][4];
        #pragma unroll
        for (int r = 0; r < 4; ++r)
            #pragma unroll
            for (int c = 0; c < 4; ++c)
                vn[r][c] = vlds[(y0 + r) * VS + (x0 + c)];
        float nv[4];
        #pragma unroll
        for (int p = 0; p < 4; ++p) nv[p] = -1e30f;
        #pragma unroll
        for (int a = 0; a < NA; ++a) {
            float w[9];                     // per-action weights from LDS
            #pragma unroll
            for (int t = 0; t < 9; ++t) w[t] = wvl[a * 9 + t];
            #pragma unroll
            for (int py = 0; py < 2; ++py)
                #pragma unroll
                for (int px = 0; px < 2; ++px) {
                    float acc = qr[py * 2 + px][a];
                    #pragma unroll
                    for (int ky = 0; ky < 3; ++ky)
                        #pragma unroll
                        for (int kx = 0; kx < 3; ++kx)
                            acc += w[ky * 3 + kx] * vn[py + ky][px + kx];
                    nv[py * 2 + px] = fmaxf(nv[py * 2 + px], acc);
                }
        }
        bool changed = false;
        #pragma unroll
        for (int py = 0; py < 2; ++py)
            #pragma unroll
            for (int px = 0; px < 2; ++px)
                changed |= (fabsf(nv[py * 2 + px] - vn[py + 1][px + 1]) > 4e-4f);
        bool check = ((it & 3) == 3) || (it == K - 1);
        if (check) {
            __syncthreads();   // B1: all reads of this sweep done
            #pragma unroll
            for (int py = 0; py < 2; ++py)
                #pragma unroll
                for (int px = 0; px < 2; ++px)
                    vlds[(y0 + py + 1) * VS + (x0 + px + 1)] = nv[py * 2 + px];
            chg[(checks + 1) & 1] = 0;          // prep next slot
            if (changed) chg[checks & 1] = 1;   // benign same-value race
            __syncthreads();   // B2: v + flags visible
            if (chg[checks & 1] == 0) break;    // full sweep with max|dv|<=tol
            ++checks;
        } else {
            // async in-place sweep: no barrier; races benign (contraction)
            #pragma unroll
            for (int py = 0; py < 2; ++py)
                #pragma unroll
                for (int px = 0; px < 2; ++px)
                    vlds[(y0 + py + 1) * VS + (x0 + px + 1)] = nv[py * 2 + px];
            __threadfence_block();   // visibility + defeat LDS caching
        }
    }

    // ---------------- phase 6: attended q + FC ----------------
    if (tid == 0) {
        int yy = att_y, xx = att_x;
        float q[NA];
        #pragma unroll
        for (int a = 0; a < NA; ++a) {
            float acc = 0.f;
            #pragma unroll
            for (int t = 0; t < 9; ++t) {
                int ly = yy + t / 3, lx = xx + t % 3;
                acc += wil[a * 9 + t] * rlds[ly * VS + lx]
                     + wvl[a * 9 + t] * vlds[ly * VS + lx];
            }
            q[a] = acc;
        }
        #pragma unroll
        for (int n = 0; n < 8; ++n) {
            float o = 0.f;
            #pragma unroll
            for (int a = 0; a < NA; ++a) o += q[a] * wfcl[n * NA + a];
            out[b * 8 + n] = o;
        }
    }

    // keep-alive for ldspad: K = kptr[0] >= 0 always, but the compiler cannot
    // prove it, so the pad (and its occupancy effect) survives DCE. Never runs.
    if (K < 0) {
        ldspad[tid] = (float)tid;
        out[b * 8 + (tid & 7)] = ldspad[(PADF - 1) - tid];
    }
}

// ---------------------------------------------------------------------------
extern "C" void kernel_launch(void* const* d_in, const int* in_sizes, int n_in,
                              void* d_out, int out_size, void* d_ws, size_t ws_size,
                              hipStream_t stream) {
    const int*   s1   = (const int*)d_in[0];
    const int*   s2   = (const int*)d_in[1];
    const float* obs  = (const float*)d_in[2];
    const int*   kptr = (const int*)d_in[3];
    const float* Wh   = (const float*)d_in[4];
    const float* bh   = (const float*)d_in[5];
    const float* Wr   = (const float*)d_in[6];
    const float* Wi   = (const float*)d_in[7];
    const float* Wvq  = (const float*)d_in[8];
    const float* Wfc  = (const float*)d_in[9];
    float* out = (float*)d_out;
    (void)ws_size; (void)d_ws; (void)in_sizes; (void)n_in; (void)out_size;

    vin_fused<<<NB, NT, 0, stream>>>(obs, Wh, bh, Wr, Wi, Wvq, Wfc,
                                     s1, s2, kptr, out);
}